// Round 4
// baseline (857.545 us; speedup 1.0000x reference)
//
#include <hip/hip_runtime.h>

#define D 128
#define KNBR 32
#define BATCH 8192
#define NCLASS 60
#define NB 16      // b rows per block (k_gemm)
#define NP 32      // (b, side) pairs per block (k_gemm)

__device__ __forceinline__ unsigned short f2bf_rne(float f) {
    unsigned int x = __float_as_uint(f);
    x = x + 0x7FFFu + ((x >> 16) & 1u);      // round-to-nearest-even
    return (unsigned short)(x >> 16);
}

// ---------------------------------------------------------------------------
// K0: prep. blk0: wqa = Wq@a[:D], wka = Wk@a[D:]
//          blk1: be = We_b @ Wuc[384:512]
//          blks 2..49: Wcomb2 = [Wk@Wuc[128:256]; Wk@Wuc[256:384]; We_w@Wuc[384:512]]
__global__ __launch_bounds__(256) void k_prep(
    const float* __restrict__ Wq, const float* __restrict__ Wk,
    const float* __restrict__ a, const float* __restrict__ Wew,
    const float* __restrict__ Web, const float* __restrict__ Wuc,
    float* __restrict__ wqa, float* __restrict__ wka,
    float* __restrict__ be, float* __restrict__ Wcomb2)
{
    __shared__ float sB[128][129];
    int blk = blockIdx.x, tid = threadIdx.x;
    if (blk == 0) {
        for (int t = tid; t < 128 * 128; t += 256) sB[t >> 7][t & 127] = Wq[t];
        __syncthreads();
        if (tid < 128) {
            float s = 0.f;
            for (int j = 0; j < D; ++j) s += sB[tid][j] * a[j];
            wqa[tid] = s;
        }
        __syncthreads();
        for (int t = tid; t < 128 * 128; t += 256) sB[t >> 7][t & 127] = Wk[t];
        __syncthreads();
        if (tid < 128) {
            float s = 0.f;
            for (int j = 0; j < D; ++j) s += sB[tid][j] * a[D + j];
            wka[tid] = s;
        }
    } else if (blk == 1) {
        if (tid < 128) {
            float acc = 0.f;
            for (int j = 0; j < D; ++j) acc += Web[j] * Wuc[(size_t)(384 + j) * D + tid];
            be[tid] = acc;
        }
    } else {
        int g  = (blk - 2) >> 4;
        int rb = ((blk - 2) & 15) * 8;
        const float* A = (g == 2) ? Wew : Wk;
        const float* B = Wuc + (size_t)(128 + g * 128) * D;
        for (int t = tid; t < 128 * 128; t += 256) sB[t >> 7][t & 127] = B[t];
        __syncthreads();
        int j = tid & 127, half = tid >> 7;
        float acc[4] = {0.f, 0.f, 0.f, 0.f};
        int r0 = rb + half * 4;
        for (int t = 0; t < 128; ++t) {
            float bv = sB[t][j];
            #pragma unroll
            for (int m = 0; m < 4; ++m)
                acc[m] = fmaf(A[(size_t)(r0 + m) * D + t], bv, acc[m]);
        }
        #pragma unroll
        for (int m = 0; m < 4; ++m)
            Wcomb2[(size_t)(g * 128 + r0 + m) * D + j] = acc[m];
    }
}

// ---------------------------------------------------------------------------
// K1: per-node scores sq/sk + bf16 conversion of the node table (fused:
// this kernel already streams all of mem once, coalesced).
__global__ __launch_bounds__(256) void k_scores(
    const float* __restrict__ mem,
    const float* __restrict__ wqa, const float* __restrict__ wka,
    float* __restrict__ nsq, float* __restrict__ nsk,
    unsigned short* __restrict__ memh)
{
    int tid = threadIdx.x, lane = tid & 31, grp = tid >> 5;
    int n0 = blockIdx.x * 64 + grp * 8;
    float4 wq4 = ((const float4*)wqa)[lane];
    float4 wk4 = ((const float4*)wka)[lane];
    #pragma unroll
    for (int i = 0; i < 8; ++i) {
        int n = n0 + i;
        float4 v = ((const float4*)(mem + (size_t)n * D))[lane];
        // bf16 copy for the gather kernel
        ushort4 hv;
        hv.x = f2bf_rne(v.x); hv.y = f2bf_rne(v.y);
        hv.z = f2bf_rne(v.z); hv.w = f2bf_rne(v.w);
        ((ushort4*)(memh + (size_t)n * D))[lane] = hv;

        float pq = v.x * wq4.x + v.y * wq4.y + v.z * wq4.z + v.w * wq4.w;
        float pk = v.x * wk4.x + v.y * wk4.y + v.z * wk4.z + v.w * wk4.w;
        #pragma unroll
        for (int m = 1; m <= 16; m <<= 1) {
            pq += __shfl_xor(pq, m, 32);
            pk += __shfl_xor(pk, m, 32);
        }
        if (lane == 0) nsq[n] = pq;
        if (lane == 1) nsk[n] = pk;
    }
}

// ---------------------------------------------------------------------------
// K2a: attention + weighted neighbor gather. ONE WAVE64 PER PAIR, uint4 of
// 8 bf16 per lane. *** DIAGNOSTIC ROUND: body runs 2x (idempotent rewrite of
// agg) with a memory clobber between reps so all loads re-execute. Dispatch
// duration ~= 2x true cost -> surfaces in top-5 if true cost > ~77 us. ***
__global__ __launch_bounds__(256) void k_attn(
    const unsigned short* __restrict__ memh,
    const float* __restrict__ nsq, const float* __restrict__ nsk,
    const int* __restrict__ src_idxs, const int* __restrict__ dst_idxs,
    const int* __restrict__ src_nb, const int* __restrict__ dst_nb,
    float* __restrict__ agg)
{
    int lane = threadIdx.x & 63;
    int wid  = threadIdx.x >> 6;
    int p    = blockIdx.x * 4 + wid;           // one pair per wave
    int side = p >> 13;                         // BATCH = 8192
    int b    = p & (BATCH - 1);

    #pragma unroll 1
    for (int rep = 0; rep < 2; ++rep) {
        asm volatile("" ::: "memory");         // defeat cross-rep load CSE

        int self_idx = (side ? dst_idxs : src_idxs)[b];
        int ik = (side ? dst_nb : src_nb)[(size_t)b * KNBR + (lane & 31)];

        float x = nsq[self_idx] + nsk[ik];
        x = (x >= 0.f) ? x : 0.2f * x;         // leaky_relu(0.2)
        float mx = x;
        #pragma unroll
        for (int m = 1; m <= 16; m <<= 1) mx = fmaxf(mx, __shfl_xor(mx, m, 32));
        float e = __expf(x - mx);
        float s = e;
        #pragma unroll
        for (int m = 1; m <= 16; m <<= 1) s += __shfl_xor(s, m, 32);
        float attn = e / s;                    // valid in both halves

        int rsub = lane >> 4;                  // 0..3
        int lr   = lane & 15;                  // dim slice

        float acc[8];
        #pragma unroll
        for (int j = 0; j < 8; ++j) acc[j] = 0.f;

        #pragma unroll
        for (int k0 = 0; k0 < KNBR; k0 += 4) {
            int   k   = k0 + rsub;
            int   ikk = __shfl(ik, k, 64);     // ik lives in lanes 0..31
            float ak  = __shfl(attn, k, 64);
            uint4 hv = *(const uint4*)(memh + (size_t)ikk * D + lr * 8);
            acc[0] = fmaf(ak, __uint_as_float(hv.x << 16),          acc[0]);
            acc[1] = fmaf(ak, __uint_as_float(hv.x & 0xFFFF0000u),  acc[1]);
            acc[2] = fmaf(ak, __uint_as_float(hv.y << 16),          acc[2]);
            acc[3] = fmaf(ak, __uint_as_float(hv.y & 0xFFFF0000u),  acc[3]);
            acc[4] = fmaf(ak, __uint_as_float(hv.z << 16),          acc[4]);
            acc[5] = fmaf(ak, __uint_as_float(hv.z & 0xFFFF0000u),  acc[5]);
            acc[6] = fmaf(ak, __uint_as_float(hv.w << 16),          acc[6]);
            acc[7] = fmaf(ak, __uint_as_float(hv.w & 0xFFFF0000u),  acc[7]);
        }
        // fold the 4 row-subsets (lanes lr, lr+16, lr+32, lr+48)
        #pragma unroll
        for (int j = 0; j < 8; ++j) {
            acc[j] += __shfl_xor(acc[j], 16, 64);
            acc[j] += __shfl_xor(acc[j], 32, 64);
        }
        float* orow = agg + (size_t)p * D + lr * 8;
        if (rsub == 0) *(float4*)orow       = make_float4(acc[0], acc[1], acc[2], acc[3]);
        if (rsub == 1) *(float4*)(orow + 4) = make_float4(acc[4], acc[5], acc[6], acc[7]);
    }
}

// ---------------------------------------------------------------------------
// K2b: msg + cls GEMMs. *** DIAGNOSTIC ROUND: entire body runs 2x
// (idempotent rewrite of out) — see k_attn note. ***
__global__ __launch_bounds__(256, 3) void k_gemm(
    const float* __restrict__ mem, const float* __restrict__ edge_feat,
    const float* __restrict__ Wuc, const float* __restrict__ Wcomb2,
    const float* __restrict__ be, const float* __restrict__ agg,
    const float* __restrict__ Wc1, const float* __restrict__ Wc2,
    const int* __restrict__ src_idxs, const int* __restrict__ dst_idxs,
    const int* __restrict__ edge_idxs,
    float* __restrict__ out)
{
    __shared__ __align__(16) float Ws[32 * 128];     // 16384 B
    __shared__ __align__(16) float nbT[128 * 33];    // 16896 B  [col][pair]
    __shared__ __align__(16) float uni[128 * 33];    // 16896 B  Ast (32x33) / msgT (128x33)
    __shared__ int s_sidx[NP];
    __shared__ int s_eidx[NB];

    int tid = threadIdx.x;
    int b0 = blockIdx.x * NB;
    int lane = tid & 31;
    int grp  = tid >> 5;
    int tr = tid >> 4, tc = tid & 15;          // 16x16 micro grid
    int lc = tid & 31, lr = tid >> 5;          // A staging lanes
    int wc = tid & 127, wk2 = tid >> 7;        // W staging lanes

    #pragma unroll 1
    for (int rep = 0; rep < 2; ++rep) {
        asm volatile("" ::: "memory");         // defeat cross-rep load CSE
        __syncthreads();                       // rep isolation

        if (tid < NP) s_sidx[tid] = ((tid >> 4) ? dst_idxs : src_idxs)[b0 + (tid & 15)];
        if (tid < NB) s_eidx[tid] = edge_idxs[b0 + tid];

        // ---------------- stage aggT from workspace (coalesced), transposed
        #pragma unroll
        for (int q = 0; q < 4; ++q) {
            int pp = grp + 8 * q;                              // 0..31
            int gp = ((pp >> 4) ? BATCH : 0) + b0 + (pp & 15); // global pair id
            float4 v = ((const float4*)(agg + (size_t)gp * D))[lane];
            nbT[(lane * 4 + 0) * 33 + pp] = v.x;
            nbT[(lane * 4 + 1) * 33 + pp] = v.y;
            nbT[(lane * 4 + 2) * 33 + pp] = v.z;
            nbT[(lane * 4 + 3) * 33 + pp] = v.w;
        }
        __syncthreads();

        // ---------------- Phase B: msg = relu(A @ [Wuc; Wcomb2] + be)
        float accB[2][8];
        #pragma unroll
        for (int i = 0; i < 2; ++i)
            #pragma unroll
            for (int j = 0; j < 8; ++j) accB[i][j] = 0.f;

        float* Ast = uni;

        // seg 0 (kt 0..3): A = self rows, staged from mem
        for (int kt = 0; kt < 4; ++kt) {
            int off = kt * 32;
            #pragma unroll
            for (int q = 0; q < 4; ++q) {
                int r = lr + 8 * q;
                Ast[lc * 33 + r] = mem[(size_t)s_sidx[r] * D + off + lc];
            }
            #pragma unroll
            for (int pp = 0; pp < 16; ++pp) {
                int kk = wk2 + 2 * pp;
                Ws[kk * 128 + wc] = Wuc[(size_t)(off + kk) * D + wc];
            }
            __syncthreads();
            #pragma unroll 8
            for (int kk = 0; kk < 32; ++kk) {
                float a0 = Ast[kk * 33 + tr * 2];
                float a1 = Ast[kk * 33 + tr * 2 + 1];
                float4 w0 = *(const float4*)&Ws[kk * 128 + tc * 4];
                float4 w1 = *(const float4*)&Ws[kk * 128 + 64 + tc * 4];
                float wr[8] = {w0.x, w0.y, w0.z, w0.w, w1.x, w1.y, w1.z, w1.w};
                #pragma unroll
                for (int j = 0; j < 8; ++j) {
                    accB[0][j] = fmaf(a0, wr[j], accB[0][j]);
                    accB[1][j] = fmaf(a1, wr[j], accB[1][j]);
                }
            }
            __syncthreads();
        }
        // segs 1-2 (kt 4..11): A read directly from nbT (no staging)
        for (int kt = 4; kt < 12; ++kt) {
            int off = (kt & 3) * 32;
            int gr0 = kt * 32 - 128;
            #pragma unroll
            for (int pp = 0; pp < 16; ++pp) {
                int kk = wk2 + 2 * pp;
                Ws[kk * 128 + wc] = Wcomb2[(size_t)(gr0 + kk) * D + wc];
            }
            __syncthreads();
            int r0 = (kt < 8) ? (tr * 2) : ((tr * 2) ^ 16);
            #pragma unroll 8
            for (int kk = 0; kk < 32; ++kk) {
                float a0 = nbT[(off + kk) * 33 + r0];
                float a1 = nbT[(off + kk) * 33 + r0 + 1];
                float4 w0 = *(const float4*)&Ws[kk * 128 + tc * 4];
                float4 w1 = *(const float4*)&Ws[kk * 128 + 64 + tc * 4];
                float wr[8] = {w0.x, w0.y, w0.z, w0.w, w1.x, w1.y, w1.z, w1.w};
                #pragma unroll
                for (int j = 0; j < 8; ++j) {
                    accB[0][j] = fmaf(a0, wr[j], accB[0][j]);
                    accB[1][j] = fmaf(a1, wr[j], accB[1][j]);
                }
            }
            __syncthreads();
        }
        // seg 3 (kt 12..15): A = edge rows, staged from edge_feat
        for (int kt = 12; kt < 16; ++kt) {
            int off = (kt & 3) * 32;
            int gr0 = kt * 32 - 128;
            #pragma unroll
            for (int q = 0; q < 4; ++q) {
                int r = lr + 8 * q;
                Ast[lc * 33 + r] = edge_feat[(size_t)s_eidx[r & 15] * D + off + lc];
            }
            #pragma unroll
            for (int pp = 0; pp < 16; ++pp) {
                int kk = wk2 + 2 * pp;
                Ws[kk * 128 + wc] = Wcomb2[(size_t)(gr0 + kk) * D + wc];
            }
            __syncthreads();
            #pragma unroll 8
            for (int kk = 0; kk < 32; ++kk) {
                float a0 = Ast[kk * 33 + tr * 2];
                float a1 = Ast[kk * 33 + tr * 2 + 1];
                float4 w0 = *(const float4*)&Ws[kk * 128 + tc * 4];
                float4 w1 = *(const float4*)&Ws[kk * 128 + 64 + tc * 4];
                float wr[8] = {w0.x, w0.y, w0.z, w0.w, w1.x, w1.y, w1.z, w1.w};
                #pragma unroll
                for (int j = 0; j < 8; ++j) {
                    accB[0][j] = fmaf(a0, wr[j], accB[0][j]);
                    accB[1][j] = fmaf(a1, wr[j], accB[1][j]);
                }
            }
            __syncthreads();
        }

        // bias + relu -> msgT[col][row]
        float* msgT = uni;
        {
            float4 bv0 = *(const float4*)&be[tc * 4];
            float4 bv1 = *(const float4*)&be[64 + tc * 4];
            float b8[8] = {bv0.x, bv0.y, bv0.z, bv0.w, bv1.x, bv1.y, bv1.z, bv1.w};
            #pragma unroll
            for (int i = 0; i < 2; ++i) {
                int r = tr * 2 + i;
                #pragma unroll
                for (int j = 0; j < 4; ++j) {
                    msgT[(tc * 4 + j) * 33 + r]      = fmaxf(accB[i][j] + b8[j], 0.f);
                    msgT[(64 + tc * 4 + j) * 33 + r] = fmaxf(accB[i][j + 4] + b8[j + 4], 0.f);
                }
            }
        }
        __syncthreads();

        // ---------------- Phase C: GEMM1 h1 = relu(msg @ Wc1)
        float accC[2][8];
        #pragma unroll
        for (int i = 0; i < 2; ++i)
            #pragma unroll
            for (int j = 0; j < 8; ++j) accC[i][j] = 0.f;

        for (int kt = 0; kt < 4; ++kt) {
            int off = kt * 32;
            #pragma unroll
            for (int pp = 0; pp < 16; ++pp) {
                int kk = wk2 + 2 * pp;
                Ws[kk * 128 + wc] = Wc1[(size_t)(off + kk) * D + wc];
            }
            __syncthreads();
            #pragma unroll 8
            for (int kk = 0; kk < 32; ++kk) {
                float a0 = msgT[(off + kk) * 33 + tr * 2];
                float a1 = msgT[(off + kk) * 33 + tr * 2 + 1];
                float4 w0 = *(const float4*)&Ws[kk * 128 + tc * 4];
                float4 w1 = *(const float4*)&Ws[kk * 128 + 64 + tc * 4];
                float wr[8] = {w0.x, w0.y, w0.z, w0.w, w1.x, w1.y, w1.z, w1.w};
                #pragma unroll
                for (int j = 0; j < 8; ++j) {
                    accC[0][j] = fmaf(a0, wr[j], accC[0][j]);
                    accC[1][j] = fmaf(a1, wr[j], accC[1][j]);
                }
            }
            __syncthreads();
        }
        // relu -> h1T overwrites msgT
        #pragma unroll
        for (int i = 0; i < 2; ++i) {
            int r = tr * 2 + i;
            #pragma unroll
            for (int j = 0; j < 4; ++j) {
                msgT[(tc * 4 + j) * 33 + r]      = fmaxf(accC[i][j], 0.f);
                msgT[(64 + tc * 4 + j) * 33 + r] = fmaxf(accC[i][j + 4], 0.f);
            }
        }
        __syncthreads();

        // ---------------- Phase C: GEMM2 logits = h1 @ Wc2  [32x128]@[128x60]
        int r2 = tid & 31;
        int cs = tid >> 5;
        float acc2[8];
        #pragma unroll
        for (int j = 0; j < 8; ++j) acc2[j] = 0.f;

        for (int kt = 0; kt < 4; ++kt) {
            int off = kt * 32;
            for (int t = tid; t < 32 * 64; t += 256) {
                int kk = t >> 6, c = t & 63;
                Ws[t] = (c < NCLASS) ? Wc2[(size_t)(off + kk) * NCLASS + c] : 0.f;
            }
            __syncthreads();
            #pragma unroll 4
            for (int kk = 0; kk < 32; ++kk) {
                float h = msgT[(off + kk) * 33 + r2];
                float4 w0 = *(const float4*)&Ws[kk * 64 + cs * 8];
                float4 w1 = *(const float4*)&Ws[kk * 64 + cs * 8 + 4];
                acc2[0] = fmaf(h, w0.x, acc2[0]);
                acc2[1] = fmaf(h, w0.y, acc2[1]);
                acc2[2] = fmaf(h, w0.z, acc2[2]);
                acc2[3] = fmaf(h, w0.w, acc2[3]);
                acc2[4] = fmaf(h, w1.x, acc2[4]);
                acc2[5] = fmaf(h, w1.y, acc2[5]);
                acc2[6] = fmaf(h, w1.z, acc2[6]);
                acc2[7] = fmaf(h, w1.w, acc2[7]);
            }
            __syncthreads();
        }
        {
            int side = r2 >> 4;
            int bb = b0 + (r2 & 15);
            size_t orow = ((size_t)side * BATCH + bb) * NCLASS;
            #pragma unroll
            for (int j = 0; j < 8; ++j) {
                int c = cs * 8 + j;
                if (c < NCLASS) out[orow + c] = acc2[j];
            }
        }
    }
}

// ---------------------------------------------------------------------------
extern "C" void kernel_launch(void* const* d_in, const int* in_sizes, int n_in,
                              void* d_out, int out_size, void* d_ws, size_t ws_size,
                              hipStream_t stream) {
    const float* mem       = (const float*)d_in[0];
    const float* edge_feat = (const float*)d_in[1];
    const float* Wq        = (const float*)d_in[2];
    const float* Wk        = (const float*)d_in[3];
    const float* a         = (const float*)d_in[4];
    const float* Wew       = (const float*)d_in[5];
    const float* Web       = (const float*)d_in[6];
    const float* Wuc       = (const float*)d_in[7];
    const float* Wc1       = (const float*)d_in[8];
    const float* Wc2       = (const float*)d_in[9];
    const int* src_idxs    = (const int*)d_in[10];
    const int* dst_idxs    = (const int*)d_in[11];
    const int* edge_idxs   = (const int*)d_in[12];
    const int* src_nb      = (const int*)d_in[13];
    const int* dst_nb      = (const int*)d_in[14];
    float* out = (float*)d_out;

    float* ws = (float*)d_ws;
    float* Wcomb2 = ws;                  // 384*128 = 49152
    float* be     = ws + 49152;          // 128
    float* wqa    = ws + 49280;          // 128
    float* wka    = ws + 49408;          // 128
    float* nsq    = ws + 49536;          // 200000
    float* nsk    = ws + 249536;         // 200000
    float* agg    = ws + 449536;         // 2*8192*128 = 2097152
    unsigned short* memh = (unsigned short*)(ws + 2546688);  // 200000*128 bf16 = 51.2 MB

    k_prep<<<50, 256, 0, stream>>>(Wq, Wk, a, Wew, Web, Wuc, wqa, wka, be, Wcomb2);
    k_scores<<<200000 / 64, 256, 0, stream>>>(mem, wqa, wka, nsq, nsk, memh);
    k_attn<<<2 * BATCH / 4, 256, 0, stream>>>(memh, nsq, nsk, src_idxs, dst_idxs,
                                              src_nb, dst_nb, agg);
    k_gemm<<<BATCH / NB, 256, 0, stream>>>(mem, edge_feat, Wuc, Wcomb2, be, agg,
                                           Wc1, Wc2,
                                           src_idxs, dst_idxs, edge_idxs, out);
}

// Round 5
// 478.896 us; speedup vs baseline: 1.7907x; 1.7907x over previous
//
#include <hip/hip_runtime.h>

#define D 128
#define KNBR 32
#define BATCH 8192
#define NCLASS 60
#define NB 16      // b rows per block (k_gemm)
#define NP 32      // (b, side) pairs per block (k_gemm)

__device__ __forceinline__ unsigned short f2bf_rne(float f) {
    unsigned int x = __float_as_uint(f);
    x = x + 0x7FFFu + ((x >> 16) & 1u);      // round-to-nearest-even
    return (unsigned short)(x >> 16);
}

// ---------------------------------------------------------------------------
// K0: prep. blk0: wqa = Wq@a[:D], wka = Wk@a[D:]
//          blk1: be = We_b @ Wuc[384:512]
//          blks 2..49: Wcomb2 = [Wk@Wuc[128:256]; Wk@Wuc[256:384]; We_w@Wuc[384:512]]
__global__ __launch_bounds__(256) void k_prep(
    const float* __restrict__ Wq, const float* __restrict__ Wk,
    const float* __restrict__ a, const float* __restrict__ Wew,
    const float* __restrict__ Web, const float* __restrict__ Wuc,
    float* __restrict__ wqa, float* __restrict__ wka,
    float* __restrict__ be, float* __restrict__ Wcomb2)
{
    __shared__ float sB[128][129];
    int blk = blockIdx.x, tid = threadIdx.x;
    if (blk == 0) {
        for (int t = tid; t < 128 * 128; t += 256) sB[t >> 7][t & 127] = Wq[t];
        __syncthreads();
        if (tid < 128) {
            float s = 0.f;
            for (int j = 0; j < D; ++j) s += sB[tid][j] * a[j];
            wqa[tid] = s;
        }
        __syncthreads();
        for (int t = tid; t < 128 * 128; t += 256) sB[t >> 7][t & 127] = Wk[t];
        __syncthreads();
        if (tid < 128) {
            float s = 0.f;
            for (int j = 0; j < D; ++j) s += sB[tid][j] * a[D + j];
            wka[tid] = s;
        }
    } else if (blk == 1) {
        if (tid < 128) {
            float acc = 0.f;
            for (int j = 0; j < D; ++j) acc += Web[j] * Wuc[(size_t)(384 + j) * D + tid];
            be[tid] = acc;
        }
    } else {
        int g  = (blk - 2) >> 4;
        int rb = ((blk - 2) & 15) * 8;
        const float* A = (g == 2) ? Wew : Wk;
        const float* B = Wuc + (size_t)(128 + g * 128) * D;
        for (int t = tid; t < 128 * 128; t += 256) sB[t >> 7][t & 127] = B[t];
        __syncthreads();
        int j = tid & 127, half = tid >> 7;
        float acc[4] = {0.f, 0.f, 0.f, 0.f};
        int r0 = rb + half * 4;
        for (int t = 0; t < 128; ++t) {
            float bv = sB[t][j];
            #pragma unroll
            for (int m = 0; m < 4; ++m)
                acc[m] = fmaf(A[(size_t)(r0 + m) * D + t], bv, acc[m]);
        }
        #pragma unroll
        for (int m = 0; m < 4; ++m)
            Wcomb2[(size_t)(g * 128 + r0 + m) * D + j] = acc[m];
    }
}

// ---------------------------------------------------------------------------
// K1: per-node scores sq/sk + bf16 conversion of the node table (fused:
// this kernel already streams all of mem once, coalesced).
__global__ __launch_bounds__(256) void k_scores(
    const float* __restrict__ mem,
    const float* __restrict__ wqa, const float* __restrict__ wka,
    float* __restrict__ nsq, float* __restrict__ nsk,
    unsigned short* __restrict__ memh)
{
    int tid = threadIdx.x, lane = tid & 31, grp = tid >> 5;
    int n0 = blockIdx.x * 64 + grp * 8;
    float4 wq4 = ((const float4*)wqa)[lane];
    float4 wk4 = ((const float4*)wka)[lane];
    #pragma unroll
    for (int i = 0; i < 8; ++i) {
        int n = n0 + i;
        float4 v = ((const float4*)(mem + (size_t)n * D))[lane];
        ushort4 hv;
        hv.x = f2bf_rne(v.x); hv.y = f2bf_rne(v.y);
        hv.z = f2bf_rne(v.z); hv.w = f2bf_rne(v.w);
        ((ushort4*)(memh + (size_t)n * D))[lane] = hv;

        float pq = v.x * wq4.x + v.y * wq4.y + v.z * wq4.z + v.w * wq4.w;
        float pk = v.x * wk4.x + v.y * wk4.y + v.z * wk4.z + v.w * wk4.w;
        #pragma unroll
        for (int m = 1; m <= 16; m <<= 1) {
            pq += __shfl_xor(pq, m, 32);
            pk += __shfl_xor(pk, m, 32);
        }
        if (lane == 0) nsq[n] = pq;
        if (lane == 1) nsk[n] = pk;
    }
}

// ---------------------------------------------------------------------------
// K2a: attention + weighted neighbor gather. One wave64 per pair, uint4 of
// 8 bf16 per lane. Output agg is now bf16 (halves agg traffic; k_gemm stages
// it into its bf16 A-matrix anyway).
__global__ __launch_bounds__(256) void k_attn(
    const unsigned short* __restrict__ memh,
    const float* __restrict__ nsq, const float* __restrict__ nsk,
    const int* __restrict__ src_idxs, const int* __restrict__ dst_idxs,
    const int* __restrict__ src_nb, const int* __restrict__ dst_nb,
    unsigned short* __restrict__ aggh)
{
    int lane = threadIdx.x & 63;
    int wid  = threadIdx.x >> 6;
    int p    = blockIdx.x * 4 + wid;           // one pair per wave
    int side = p >> 13;                         // BATCH = 8192
    int b    = p & (BATCH - 1);

    int self_idx = (side ? dst_idxs : src_idxs)[b];
    int ik = (side ? dst_nb : src_nb)[(size_t)b * KNBR + (lane & 31)];

    float x = nsq[self_idx] + nsk[ik];
    x = (x >= 0.f) ? x : 0.2f * x;             // leaky_relu(0.2)
    float mx = x;
    #pragma unroll
    for (int m = 1; m <= 16; m <<= 1) mx = fmaxf(mx, __shfl_xor(mx, m, 32));
    float e = __expf(x - mx);
    float s = e;
    #pragma unroll
    for (int m = 1; m <= 16; m <<= 1) s += __shfl_xor(s, m, 32);
    float attn = e / s;                        // valid in both halves

    int rsub = lane >> 4;                      // 0..3
    int lr   = lane & 15;                      // dim slice

    float acc[8];
    #pragma unroll
    for (int j = 0; j < 8; ++j) acc[j] = 0.f;

    #pragma unroll
    for (int k0 = 0; k0 < KNBR; k0 += 4) {
        int   k   = k0 + rsub;
        int   ikk = __shfl(ik, k, 64);         // ik lives in lanes 0..31
        float ak  = __shfl(attn, k, 64);
        uint4 hv = *(const uint4*)(memh + (size_t)ikk * D + lr * 8);
        acc[0] = fmaf(ak, __uint_as_float(hv.x << 16),          acc[0]);
        acc[1] = fmaf(ak, __uint_as_float(hv.x & 0xFFFF0000u),  acc[1]);
        acc[2] = fmaf(ak, __uint_as_float(hv.y << 16),          acc[2]);
        acc[3] = fmaf(ak, __uint_as_float(hv.y & 0xFFFF0000u),  acc[3]);
        acc[4] = fmaf(ak, __uint_as_float(hv.z << 16),          acc[4]);
        acc[5] = fmaf(ak, __uint_as_float(hv.z & 0xFFFF0000u),  acc[5]);
        acc[6] = fmaf(ak, __uint_as_float(hv.w << 16),          acc[6]);
        acc[7] = fmaf(ak, __uint_as_float(hv.w & 0xFFFF0000u),  acc[7]);
    }
    #pragma unroll
    for (int j = 0; j < 8; ++j) {
        acc[j] += __shfl_xor(acc[j], 16, 64);
        acc[j] += __shfl_xor(acc[j], 32, 64);
    }
    if (rsub == 0) {
        ushort4 hv;
        hv.x = f2bf_rne(acc[0]); hv.y = f2bf_rne(acc[1]);
        hv.z = f2bf_rne(acc[2]); hv.w = f2bf_rne(acc[3]);
        *(ushort4*)(aggh + (size_t)p * D + lr * 8) = hv;
    } else if (rsub == 1) {
        ushort4 hv;
        hv.x = f2bf_rne(acc[4]); hv.y = f2bf_rne(acc[5]);
        hv.z = f2bf_rne(acc[6]); hv.w = f2bf_rne(acc[7]);
        *(ushort4*)(aggh + (size_t)p * D + lr * 8 + 4) = hv;
    }
}

// ---------------------------------------------------------------------------
// K2b: msg + cls GEMMs, RESTRUCTURED: all random gathers (self rows via bf16
// memh, h_own/h_other via bf16 aggh, edge rows converted inline) are hoisted
// into ONE staging phase building Afull[512 cols][32 pairs] (bf16) in LDS.
// The 16-kt weight loop then touches only sequential weight reads — one
// random-latency wait per block instead of 12, and weights stay L2-hot.
// msgT (fp32) overlays the dead Afull. LDS ~50 KB.
__global__ __launch_bounds__(256, 2) void k_gemm(
    const unsigned short* __restrict__ memh, const float* __restrict__ edge_feat,
    const float* __restrict__ Wuc, const float* __restrict__ Wcomb2,
    const float* __restrict__ be, const unsigned short* __restrict__ aggh,
    const float* __restrict__ Wc1, const float* __restrict__ Wc2,
    const int* __restrict__ src_idxs, const int* __restrict__ dst_idxs,
    const int* __restrict__ edge_idxs,
    float* __restrict__ out)
{
    __shared__ __align__(16) unsigned short Afull[512 * 34];   // 34816 B, [col][pair] bf16
    __shared__ __align__(16) float Ws[32 * 128];               // 16384 B

    int tid = threadIdx.x;
    int b0 = blockIdx.x * NB;

    // ---------------- hoisted A staging: [self | h_own | h_other | e]
    // self rows (cols 0..127), 512 tasks = (pair, 8-col chunk)
    for (int t = tid; t < 512; t += 256) {
        int p = t >> 4, c0 = (t & 15) * 8;
        int sidx = ((p >> 4) ? dst_idxs : src_idxs)[b0 + (p & 15)];
        uint4 v = *(const uint4*)(memh + (size_t)sidx * D + c0);
        const unsigned short* us = (const unsigned short*)&v;
        #pragma unroll
        for (int j = 0; j < 8; ++j) Afull[(c0 + j) * 34 + p] = us[j];
    }
    // h_own (cols 128..255)
    for (int t = tid; t < 512; t += 256) {
        int p = t >> 4, c0 = (t & 15) * 8;
        int gp = ((p >> 4) ? BATCH : 0) + b0 + (p & 15);
        uint4 v = *(const uint4*)(aggh + (size_t)gp * D + c0);
        const unsigned short* us = (const unsigned short*)&v;
        #pragma unroll
        for (int j = 0; j < 8; ++j) Afull[(128 + c0 + j) * 34 + p] = us[j];
    }
    // h_other (cols 256..383)
    for (int t = tid; t < 512; t += 256) {
        int p = t >> 4, c0 = (t & 15) * 8;
        int gp = ((p >> 4) ? 0 : BATCH) + b0 + (p & 15);   // opposite side
        uint4 v = *(const uint4*)(aggh + (size_t)gp * D + c0);
        const unsigned short* us = (const unsigned short*)&v;
        #pragma unroll
        for (int j = 0; j < 8; ++j) Afull[(256 + c0 + j) * 34 + p] = us[j];
    }
    // edge rows (cols 384..511), shared by pair e and e+16; fp32 -> bf16
    {
        int e = tid >> 4, c0 = (tid & 15) * 8;
        int eidx = edge_idxs[b0 + e];
        const float* src = edge_feat + (size_t)eidx * D + c0;
        float4 v0 = *(const float4*)src;
        float4 v1 = *(const float4*)(src + 4);
        unsigned short us[8];
        us[0] = f2bf_rne(v0.x); us[1] = f2bf_rne(v0.y);
        us[2] = f2bf_rne(v0.z); us[3] = f2bf_rne(v0.w);
        us[4] = f2bf_rne(v1.x); us[5] = f2bf_rne(v1.y);
        us[6] = f2bf_rne(v1.z); us[7] = f2bf_rne(v1.w);
        #pragma unroll
        for (int j = 0; j < 8; ++j) {
            Afull[(384 + c0 + j) * 34 + e]      = us[j];
            Afull[(384 + c0 + j) * 34 + e + 16] = us[j];
        }
    }
    __syncthreads();

    // ---------------- Phase B: msg = relu(A @ Wfull + be), uniform 512-K loop
    int tr = tid >> 4, tc = tid & 15;          // 16x16 micro grid, 2 rows x 8 cols
    int wc = tid & 127, wk2 = tid >> 7;        // W staging lanes
    float accB[2][8];
    #pragma unroll
    for (int i = 0; i < 2; ++i)
        #pragma unroll
        for (int j = 0; j < 8; ++j) accB[i][j] = 0.f;

    for (int kt = 0; kt < 16; ++kt) {
        const float* Wsrc = (kt < 4) ? (Wuc + (size_t)(kt * 32) * D)
                                     : (Wcomb2 + (size_t)(kt * 32 - 128) * D);
        #pragma unroll
        for (int pp = 0; pp < 16; ++pp) {
            int kk = wk2 + 2 * pp;
            Ws[kk * 128 + wc] = Wsrc[(size_t)kk * D + wc];
        }
        __syncthreads();
        const unsigned short* Acol = Afull + (size_t)(kt * 32) * 34 + 2 * tr;
        #pragma unroll 8
        for (int kk = 0; kk < 32; ++kk) {
            unsigned int av = *(const unsigned int*)(Acol + kk * 34);
            float a0 = __uint_as_float(av << 16);
            float a1 = __uint_as_float(av & 0xFFFF0000u);
            float4 w0 = *(const float4*)&Ws[kk * 128 + tc * 4];
            float4 w1 = *(const float4*)&Ws[kk * 128 + 64 + tc * 4];
            float wr[8] = {w0.x, w0.y, w0.z, w0.w, w1.x, w1.y, w1.z, w1.w};
            #pragma unroll
            for (int j = 0; j < 8; ++j) {
                accB[0][j] = fmaf(a0, wr[j], accB[0][j]);
                accB[1][j] = fmaf(a1, wr[j], accB[1][j]);
            }
        }
        __syncthreads();
    }

    // bias + relu -> msgT[col][row], fp32, overlays the now-dead Afull
    float* msgT = (float*)Afull;               // [128][33] = 16896 B < 34816 B
    {
        float4 bv0 = *(const float4*)&be[tc * 4];
        float4 bv1 = *(const float4*)&be[64 + tc * 4];
        float b8[8] = {bv0.x, bv0.y, bv0.z, bv0.w, bv1.x, bv1.y, bv1.z, bv1.w};
        #pragma unroll
        for (int i = 0; i < 2; ++i) {
            int r = tr * 2 + i;
            #pragma unroll
            for (int j = 0; j < 4; ++j) {
                msgT[(tc * 4 + j) * 33 + r]      = fmaxf(accB[i][j] + b8[j], 0.f);
                msgT[(64 + tc * 4 + j) * 33 + r] = fmaxf(accB[i][j + 4] + b8[j + 4], 0.f);
            }
        }
    }
    __syncthreads();

    // ---------------- Phase C: GEMM1 h1 = relu(msg @ Wc1)
    float accC[2][8];
    #pragma unroll
    for (int i = 0; i < 2; ++i)
        #pragma unroll
        for (int j = 0; j < 8; ++j) accC[i][j] = 0.f;

    for (int kt = 0; kt < 4; ++kt) {
        int off = kt * 32;
        #pragma unroll
        for (int pp = 0; pp < 16; ++pp) {
            int kk = wk2 + 2 * pp;
            Ws[kk * 128 + wc] = Wc1[(size_t)(off + kk) * D + wc];
        }
        __syncthreads();
        #pragma unroll 8
        for (int kk = 0; kk < 32; ++kk) {
            float a0 = msgT[(off + kk) * 33 + tr * 2];
            float a1 = msgT[(off + kk) * 33 + tr * 2 + 1];
            float4 w0 = *(const float4*)&Ws[kk * 128 + tc * 4];
            float4 w1 = *(const float4*)&Ws[kk * 128 + 64 + tc * 4];
            float wr[8] = {w0.x, w0.y, w0.z, w0.w, w1.x, w1.y, w1.z, w1.w};
            #pragma unroll
            for (int j = 0; j < 8; ++j) {
                accC[0][j] = fmaf(a0, wr[j], accC[0][j]);
                accC[1][j] = fmaf(a1, wr[j], accC[1][j]);
            }
        }
        __syncthreads();
    }
    // relu -> h1T overwrites msgT
    #pragma unroll
    for (int i = 0; i < 2; ++i) {
        int r = tr * 2 + i;
        #pragma unroll
        for (int j = 0; j < 4; ++j) {
            msgT[(tc * 4 + j) * 33 + r]      = fmaxf(accC[i][j], 0.f);
            msgT[(64 + tc * 4 + j) * 33 + r] = fmaxf(accC[i][j + 4], 0.f);
        }
    }
    __syncthreads();

    // ---------------- Phase C: GEMM2 logits = h1 @ Wc2  [32x128]@[128x60]
    int r2 = tid & 31;
    int cs = tid >> 5;
    float acc2[8];
    #pragma unroll
    for (int j = 0; j < 8; ++j) acc2[j] = 0.f;

    for (int kt = 0; kt < 4; ++kt) {
        int off = kt * 32;
        for (int t = tid; t < 32 * 64; t += 256) {
            int kk = t >> 6, c = t & 63;
            Ws[t] = (c < NCLASS) ? Wc2[(size_t)(off + kk) * NCLASS + c] : 0.f;
        }
        __syncthreads();
        #pragma unroll 4
        for (int kk = 0; kk < 32; ++kk) {
            float h = msgT[(off + kk) * 33 + r2];
            float4 w0 = *(const float4*)&Ws[kk * 64 + cs * 8];
            float4 w1 = *(const float4*)&Ws[kk * 64 + cs * 8 + 4];
            acc2[0] = fmaf(h, w0.x, acc2[0]);
            acc2[1] = fmaf(h, w0.y, acc2[1]);
            acc2[2] = fmaf(h, w0.z, acc2[2]);
            acc2[3] = fmaf(h, w0.w, acc2[3]);
            acc2[4] = fmaf(h, w1.x, acc2[4]);
            acc2[5] = fmaf(h, w1.y, acc2[5]);
            acc2[6] = fmaf(h, w1.z, acc2[6]);
            acc2[7] = fmaf(h, w1.w, acc2[7]);
        }
        __syncthreads();
    }
    {
        int side = r2 >> 4;
        int bb = b0 + (r2 & 15);
        size_t orow = ((size_t)side * BATCH + bb) * NCLASS;
        #pragma unroll
        for (int j = 0; j < 8; ++j) {
            int c = cs * 8 + j;
            if (c < NCLASS) out[orow + c] = acc2[j];
        }
    }
}

// ---------------------------------------------------------------------------
extern "C" void kernel_launch(void* const* d_in, const int* in_sizes, int n_in,
                              void* d_out, int out_size, void* d_ws, size_t ws_size,
                              hipStream_t stream) {
    const float* mem       = (const float*)d_in[0];
    const float* edge_feat = (const float*)d_in[1];
    const float* Wq        = (const float*)d_in[2];
    const float* Wk        = (const float*)d_in[3];
    const float* a         = (const float*)d_in[4];
    const float* Wew       = (const float*)d_in[5];
    const float* Web       = (const float*)d_in[6];
    const float* Wuc       = (const float*)d_in[7];
    const float* Wc1       = (const float*)d_in[8];
    const float* Wc2       = (const float*)d_in[9];
    const int* src_idxs    = (const int*)d_in[10];
    const int* dst_idxs    = (const int*)d_in[11];
    const int* edge_idxs   = (const int*)d_in[12];
    const int* src_nb      = (const int*)d_in[13];
    const int* dst_nb      = (const int*)d_in[14];
    float* out = (float*)d_out;

    float* ws = (float*)d_ws;
    float* Wcomb2 = ws;                  // 384*128 = 49152
    float* be     = ws + 49152;          // 128
    float* wqa    = ws + 49280;          // 128
    float* wka    = ws + 49408;          // 128
    float* nsq    = ws + 49536;          // 200000
    float* nsk    = ws + 249536;         // 200000
    unsigned short* aggh = (unsigned short*)(ws + 449536);   // 2*8192*128 bf16 = 4.2 MB
    unsigned short* memh = (unsigned short*)(ws + 2546688);  // 200000*128 bf16 = 51.2 MB

    k_prep<<<50, 256, 0, stream>>>(Wq, Wk, a, Wew, Web, Wuc, wqa, wka, be, Wcomb2);
    k_scores<<<200000 / 64, 256, 0, stream>>>(mem, wqa, wka, nsq, nsk, memh);
    k_attn<<<2 * BATCH / 4, 256, 0, stream>>>(memh, nsq, nsk, src_idxs, dst_idxs,
                                              src_nb, dst_nb, aggh);
    k_gemm<<<BATCH / NB, 256, 0, stream>>>(memh, edge_feat, Wuc, Wcomb2, be, aggh,
                                           Wc1, Wc2,
                                           src_idxs, dst_idxs, edge_idxs, out);
}